// Round 7
// baseline (551.159 us; speedup 1.0000x reference)
//
#include <hip/hip_runtime.h>

#define BB   4
#define SS   2048
#define HD   1024
#define NHH  16
#define DD   64
#define FFF  4096
#define BS   (BB*SS)   // 8192 rows
#define BHN  (BB*NHH)  // 64 (b,h) pairs

typedef __attribute__((ext_vector_type(8))) short v8s;   // 8 bf16 (4 VGPR)
typedef __attribute__((ext_vector_type(4))) short v4s;
typedef __attribute__((ext_vector_type(4))) float v4f;

__device__ __forceinline__ short f2bf(float f) {
    union { float f; unsigned u; } v; v.f = f;
    unsigned r = (v.u + 0x7fffu + ((v.u >> 16) & 1u)) >> 16;
    return (short)r;
}
__device__ __forceinline__ float bf2f(short s) {
    union { unsigned u; float f; } v; v.u = ((unsigned)(unsigned short)s) << 16;
    return v.f;
}
// packed bf16 truncation of two floats: 1 VALU op (v_perm_b32)
__device__ __forceinline__ unsigned pktrunc(float lo, float hi) {
    return __builtin_amdgcn_perm(__builtin_bit_cast(unsigned, hi),
                                 __builtin_bit_cast(unsigned, lo), 0x07060302u);
}
__device__ __forceinline__ v4f mfma16(v8s a, v8s b, v4f c) {
    return __builtin_amdgcn_mfma_f32_16x16x32_bf16(a, b, c, 0, 0, 0);
}
// async global->LDS, 16B per lane; LDS dest = wave-uniform base + lane*16
__device__ __forceinline__ void cp16(void* lds, const void* g) {
    __builtin_amdgcn_global_load_lds(
        (const __attribute__((address_space(1))) unsigned*)g,
        (__attribute__((address_space(3))) unsigned*)lds, 16, 0, 0);
}

// ---------------- small prep kernels ----------------

__global__ __launch_bounds__(256) void cast_bf16(const float* __restrict__ X,
                                                 short* __restrict__ Y, int n) {
    const int i = (blockIdx.x * 256 + threadIdx.x) * 4;
    if (i < n) {
        const float4 v = *(const float4*)(X + i);
        v4s o = { f2bf(v.x), f2bf(v.y), f2bf(v.z), f2bf(v.w) };
        *(v4s*)(Y + i) = o;
    }
}

__global__ __launch_bounds__(256) void rope_tab(float* __restrict__ C, float* __restrict__ Sn) {
    const int i = blockIdx.x * 256 + threadIdx.x;   // i < SS*32
    const int s = i >> 5, di = i & 31;
    const float inv = powf(10000.f, -(float)(2 * di) * (1.f / 64.f));
    const float a = (float)s * inv;
    C[i]  = cosf(a);
    Sn[i] = sinf(a);
}

// All 6 weight transposes fused into one launch (flat grid 3072 blocks).
// W [K][N] fp32 -> WT [N][K] bf16, 64x64 tiles.
__global__ __launch_bounds__(256) void transW_all(
    const float* __restrict__ Wq, const float* __restrict__ Wk,
    const float* __restrict__ Wv, const float* __restrict__ Wo,
    const float* __restrict__ W1, const float* __restrict__ W2,
    short* __restrict__ WqkvT, short* __restrict__ WoT,
    short* __restrict__ W1T, short* __restrict__ W2T)
{
    const int id = blockIdx.x;
    const float* W; short* WT; int K, N, bx, by;
    if (id < 768) {            // Wq,Wk,Wv -> WqkvT (256 blocks each, 16x16)
        const int m = id >> 8;
        W = (m == 0) ? Wq : (m == 1) ? Wk : Wv;
        WT = WqkvT + (size_t)m * HD * HD;
        K = HD; N = HD; const int r = id & 255; bx = r & 15; by = r >> 4;
    } else if (id < 1024) {    // Wo (16x16)
        W = Wo; WT = WoT; K = HD; N = HD;
        const int r = id - 768; bx = r & 15; by = r >> 4;
    } else if (id < 2048) {    // W1: K=1024, N=4096 (64x16)
        W = W1; WT = W1T; K = HD; N = FFF;
        const int r = id - 1024; bx = r & 63; by = r >> 6;
    } else {                   // W2: K=4096, N=1024 (16x64)
        W = W2; WT = W2T; K = FFF; N = HD;
        const int r = id - 2048; bx = r & 15; by = r >> 4;
    }
    __shared__ float T[64][65];
    const int t = threadIdx.x;
    const int r0 = by * 64, c0 = bx * 64;
#pragma unroll
    for (int i = 0; i < 4; i++) {
        const int lin = t + 256 * i;
        const int r = lin >> 4, c = (lin & 15) * 4;
        const float4 v = *(const float4*)(W + (size_t)(r0 + r) * N + c0 + c);
        T[r][c] = v.x; T[r][c+1] = v.y; T[r][c+2] = v.z; T[r][c+3] = v.w;
    }
    __syncthreads();
#pragma unroll
    for (int i = 0; i < 4; i++) {
        const int lin = t + 256 * i;
        const int n = lin >> 4, k = (lin & 15) * 4;
        v4s o = { f2bf(T[k][n]), f2bf(T[k+1][n]), f2bf(T[k+2][n]), f2bf(T[k+3][n]) };
        *(v4s*)(WT + (size_t)(c0 + n) * K + r0 + k) = o;
    }
}

// ---------------- GEMM 128x128, BK=32, 4-buffer ring, counted vmcnt --------
// 4 waves (2x2), per-wave 64x64, acc[4][4]. Staging/swizzle = R0's proven
// gemm_bt BK=32 pattern (0 bank conflicts). LDS 64 KB (4 x 16 KB ring).
// Pipeline depth 2: iter t stages tile t+2, computes tile t, then
//   s_waitcnt vmcnt(4)  -> waits ONLY for tile t+1 (issued a full iteration
//                          ago), tile t+2's 4 loads stay in flight across
//   s_barrier              the raw barrier (no vmcnt-0 drain).
// R6 post-mortem: __syncthreads drained vmcnt(0) on the JUST-issued tile ->
// ~2700 cyc/step of load-latency wait (MfmaUtil 31%). This gives each tile's
// loads ~2 iterations to land. Per-wave vmcnt counts its own 4 cp16s; the
// barrier makes the guarantee collective. Tail: last two iters use vmcnt(0).
// WAR: stage (t+2)&3 overwrites tile t-2's buffer, read 2 barriers earlier.
// EPI 0: fused QKV (Q scale+rope, K rope, V transposed into out2)
// EPI 2: fp32 out + fp32 residual      EPI 3: bf16 GELU
// EPI 4: fp32 out + bf16 residual

template <int EPI>
__global__ __launch_bounds__(256, 2) void gemm128(
    const short* __restrict__ A, const short* __restrict__ Bt,
    const float* __restrict__ bias, const float* __restrict__ bias2,
    const float* __restrict__ bias3, void* __restrict__ out,
    void* __restrict__ out2, const void* __restrict__ resid,
    const float* __restrict__ ropeC, const float* __restrict__ ropeS,
    int M, int N, int K, float oscale)
{
    __shared__ short As[4][128 * 32];   // 32 KB
    __shared__ short Bs[4][128 * 32];   // 32 KB
    const int tid = threadIdx.x;
    const int wave = tid >> 6, lane = tid & 63;
    const int quad = lane >> 4, l16 = lane & 15;
    const int wm = wave & 1, wn = wave >> 1;
    const int m0 = blockIdx.x * 128, n0 = blockIdx.y * 128;

    v4f acc[4][4];
#pragma unroll
    for (int i = 0; i < 4; i++)
#pragma unroll
        for (int j = 0; j < 4; j++) { v4f z = {0.f, 0.f, 0.f, 0.f}; acc[i][j] = z; }

    // staging: wave w covers rows w*32..w*32+31 (2 cp16 of 16 rows each, A and B)
    const int r4 = lane >> 2;                       // row within 16
    const int g4 = (lane & 3) ^ ((lane >> 3) & 3);  // swizzled source chunk
    const short* Asrc = A  + (size_t)(m0 + wave * 32 + r4) * K + g4 * 8;
    const short* Bsrc = Bt + (size_t)(n0 + wave * 32 + r4) * K + g4 * 8;
    const int pshift = (l16 >> 1) & 3;              // fragment-read swizzle

    auto stage = [&](int buf, int kofs) {
        cp16(&As[buf][wave * 1024],       Asrc + kofs);
        cp16(&As[buf][wave * 1024 + 512], Asrc + (size_t)16 * K + kofs);
        cp16(&Bs[buf][wave * 1024],       Bsrc + kofs);
        cp16(&Bs[buf][wave * 1024 + 512], Bsrc + (size_t)16 * K + kofs);
    };

    // prologue: tiles 0 and 1 in flight; wait for tile 0 only
    stage(0, 0);
    stage(1, 32);
    asm volatile("s_waitcnt vmcnt(4)" ::: "memory");
    __builtin_amdgcn_s_barrier();

    const int NT = K >> 5;
    for (int it = 0; it < NT; ++it) {
        const int cur = it & 3;
        const bool more = (it + 2) < NT;
        if (more) stage((it + 2) & 3, (it + 2) << 5);
        v8s af[4], bfr[4];
#pragma unroll
        for (int i = 0; i < 4; i++)
            af[i] = *(const v8s*)(&As[cur][(wm * 64 + i * 16 + l16) * 32
                                           + (quad ^ pshift) * 8]);
#pragma unroll
        for (int j = 0; j < 4; j++)
            bfr[j] = *(const v8s*)(&Bs[cur][(wn * 64 + j * 16 + l16) * 32
                                            + (quad ^ pshift) * 8]);
#pragma unroll
        for (int i = 0; i < 4; i++)
#pragma unroll
            for (int j = 0; j < 4; j++)
                acc[i][j] = mfma16(af[i], bfr[j], acc[i][j]);
        if (more) asm volatile("s_waitcnt vmcnt(4)" ::: "memory");
        else      asm volatile("s_waitcnt vmcnt(0)" ::: "memory");
        __builtin_amdgcn_s_barrier();
    }

#pragma unroll
    for (int j = 0; j < 4; j++) {
        const int col = n0 + wn * 64 + j * 16 + l16;
        if constexpr (EPI == 0) {
            const int h = col >> 10;   // block-uniform: 0=Q, 1=K, 2=V
            const float* bp = (h == 0) ? bias : ((h == 1) ? bias2 : bias3);
            const float bval = bp[col & 1023];
            const int d = col & 63;
            const int hh = (col >> 6) & 15;
            if (h == 2) {
                // V: transpose-store 4 consecutive s per (i,j) -> Vt[bh][d][s]
#pragma unroll
                for (int i = 0; i < 4; i++) {
                    const int row0 = m0 + wm * 64 + i * 16 + quad * 4;
                    const int b_ = row0 >> 11, s0 = row0 & (SS - 1);
                    v4s ov = { f2bf(acc[i][j][0] + bval), f2bf(acc[i][j][1] + bval),
                               f2bf(acc[i][j][2] + bval), f2bf(acc[i][j][3] + bval) };
                    *(v4s*)((short*)out2 + ((size_t)(b_ * NHH + hh) * DD + d) * SS + s0) = ov;
                }
            } else {
#pragma unroll
                for (int i = 0; i < 4; i++) {
#pragma unroll
                    for (int r = 0; r < 4; r++) {
                        const int row = m0 + wm * 64 + i * 16 + quad * 4 + r;
                        float v = acc[i][j][r] + bval;
                        if (h == 0) v *= oscale;
                        const int s = row & (SS - 1);
                        const float cv = ropeC[s * 32 + (d >> 1)];
                        const float sv = ropeS[s * 32 + (d >> 1)];
                        const float partner = __shfl_xor(v, 1);
                        const float o = (d & 1) ? fmaf(v, cv, partner * sv)
                                                : fmaf(v, cv, -partner * sv);
                        const int b_ = row >> 11;
                        ((short*)out)[(size_t)h * (BHN * SS * DD)
                                      + (((size_t)(b_ * NHH + hh)) * SS + s) * DD + d] = f2bf(o);
                    }
                }
            }
        } else if constexpr (EPI == 3) {
            const float bval = bias[col];
#pragma unroll
            for (int i = 0; i < 4; i++) {
#pragma unroll
                for (int r = 0; r < 4; r++) {
                    const int row = m0 + wm * 64 + i * 16 + quad * 4 + r;
                    float v = acc[i][j][r] + bval;
                    // gelu(v) = v * sigmoid(2u), u = 0.7978845608*(v + 0.044715 v^3)
                    const float tq = v * v;
                    const float u = v * fmaf(0.035677408136f, tq, 0.7978845608028654f);
                    const float e = __builtin_amdgcn_exp2f(-2.8853900817779268f * u);
                    const float g = v * __builtin_amdgcn_rcpf(1.f + e);
                    ((short*)out)[(size_t)row * N + col] = f2bf(g);
                }
            }
        } else {
            const float bval = bias[col];
#pragma unroll
            for (int i = 0; i < 4; i++) {
#pragma unroll
                for (int r = 0; r < 4; r++) {
                    const int row = m0 + wm * 64 + i * 16 + quad * 4 + r;
                    float v = acc[i][j][r] + bval;
                    if constexpr (EPI == 2) v += ((const float*)resid)[(size_t)row * N + col];
                    else                    v += bf2f(((const short*)resid)[(size_t)row * N + col]);
                    ((float*)out)[(size_t)row * N + col] = v;
                }
            }
        }
    }
}

// ---------------- flash attention (single-buffered, R0-proven) --------------
// grid (64 bh fast, SS/128 q-tiles); block 256 = 4 waves; wave owns 32 q rows.
// S^T formulation; no max-subtraction (scores bounded); Q pre-scaled by
// 0.125*log2e in the fused-QKV epilogue, so P = exp2(score).
// R5 lesson: double-buffering K/V (44.5 KB LDS) cut occupancy 33.6->22.3%
// and REGRESSED 90.6->103 us — this kernel lives off cross-block TLP.
__global__ __launch_bounds__(256, 4) void attn_kernel(
    const short* __restrict__ Qh, const short* __restrict__ Kh,
    const short* __restrict__ Vt, short* __restrict__ ctx)
{
    __shared__ short Ks[64 * 64];     // [key][d-chunk swizzled]
    __shared__ short Vs[64 * 64];     // [d][key-chunk swizzled]
    __shared__ short Ps[4][16 * 88];  // per-wave P buffer [q][key], pitch 88
    __shared__ float Li[4][32];
    const int bh = blockIdx.x, q0 = blockIdx.y * 128;
    const int t = threadIdx.x, wave = t >> 6, lane = t & 63;
    const int quad = lane >> 4, l16 = lane & 15;

    // Q fragments (B-operand): lane = query q0 + wave*32 + qs*16 + l16
    const short* qp = Qh + ((size_t)bh * SS + q0 + wave * 32 + l16) * DD;
    v8s bq[2][2];
    bq[0][0] = *(const v8s*)(qp + quad * 8);
    bq[0][1] = *(const v8s*)(qp + 32 + quad * 8);
    bq[1][0] = *(const v8s*)(qp + (size_t)16 * DD + quad * 8);
    bq[1][1] = *(const v8s*)(qp + (size_t)16 * DD + 32 + quad * 8);

    v4f o[2][4];
#pragma unroll
    for (int qs = 0; qs < 2; qs++)
#pragma unroll
        for (int c = 0; c < 4; c++) { v4f z = {0.f, 0.f, 0.f, 0.f}; o[qs][c] = z; }
    float li[2] = {0.f, 0.f};

    const short* Kb = Kh + (size_t)bh * SS * DD;
    const short* Vb = Vt + (size_t)bh * DD * SS;
    const int r8 = lane >> 3;                      // row within 8
    const int g8 = (lane & 7) ^ (r8 & 7);          // swizzled source chunk
    short* Psw = (short*)Ps[wave];
    const int xsw = l16 & 7;                       // fragment-read swizzle

    for (int kt = 0; kt < SS; kt += 64) {
        __syncthreads();
        cp16(Ks + wave * 1024,       Kb + (size_t)(kt + wave * 16 + r8) * DD + g8 * 8);
        cp16(Ks + wave * 1024 + 512, Kb + (size_t)(kt + wave * 16 + 8 + r8) * DD + g8 * 8);
        cp16(Vs + wave * 1024,       Vb + (size_t)(wave * 16 + r8) * SS + kt + g8 * 8);
        cp16(Vs + wave * 1024 + 512, Vb + (size_t)(wave * 16 + 8 + r8) * SS + kt + g8 * 8);
        __syncthreads();

        // S^T = K Q^T : D[m=key][n=q]; sc[qs][c][r] = score(key=c*16+quad*4+r, q)
        v4f sc[2][4];
#pragma unroll
        for (int c = 0; c < 4; c++) {
            const v8s k0f = *(const v8s*)(Ks + (c * 16 + l16) * 64 + ((quad    ) ^ xsw) * 8);
            const v8s k1f = *(const v8s*)(Ks + (c * 16 + l16) * 64 + ((quad + 4) ^ xsw) * 8);
#pragma unroll
            for (int qs = 0; qs < 2; qs++) {
                v4f z = {0.f, 0.f, 0.f, 0.f};
                z = mfma16(k0f, bq[qs][0], z);
                z = mfma16(k1f, bq[qs][1], z);
                sc[qs][c] = z;
            }
        }

        // softmax (no max): p = exp2(score); li in fp32; P -> LDS via packed
        // bf16 TRUNCATION (v_perm_b32, 1 op / 2 elems) + ds_write_b64
        v8s pa[2][2];
#pragma unroll
        for (int qs = 0; qs < 2; qs++) {
            float lp = 0.f;
#pragma unroll
            for (int c = 0; c < 4; c++) {
#pragma unroll
                for (int r = 0; r < 4; r++) {
                    const float p = __builtin_amdgcn_exp2f(sc[qs][c][r]);
                    sc[qs][c][r] = p;
                    lp += p;
                }
            }
            li[qs] += lp;
            short* pw = Psw + l16 * 88;
#pragma unroll
            for (int c = 0; c < 4; c++) {
                uint2 w;
                w.x = pktrunc(sc[qs][c][0], sc[qs][c][1]);
                w.y = pktrunc(sc[qs][c][2], sc[qs][c][3]);
                *(uint2*)(pw + c * 16 + quad * 4) = w;
            }
            pa[qs][0] = *(const v8s*)(Psw + l16 * 88 + quad * 8);
            pa[qs][1] = *(const v8s*)(Psw + l16 * 88 + 32 + quad * 8);
        }

        // O += P V : A=P[q][key], B=Vs[d][key]
#pragma unroll
        for (int c = 0; c < 4; c++) {
            const v8s v0f = *(const v8s*)(Vs + (c * 16 + l16) * 64 + ((quad    ) ^ xsw) * 8);
            const v8s v1f = *(const v8s*)(Vs + (c * 16 + l16) * 64 + ((quad + 4) ^ xsw) * 8);
#pragma unroll
            for (int qs = 0; qs < 2; qs++) {
                o[qs][c] = mfma16(pa[qs][0], v0f, o[qs][c]);
                o[qs][c] = mfma16(pa[qs][1], v1f, o[qs][c]);
            }
        }
    }

    // finalize li (cross-quad, once) and divide
    float linv[2][4];
#pragma unroll
    for (int qs = 0; qs < 2; qs++) {
        float lf = li[qs];
        lf += __shfl_xor(lf, 16);
        lf += __shfl_xor(lf, 32);
        if (quad == 0) Li[wave][qs * 16 + l16] = lf;
    }
    __syncthreads();
#pragma unroll
    for (int qs = 0; qs < 2; qs++) {
        const v4f lv = *(const v4f*)(&Li[wave][qs * 16 + quad * 4]);
#pragma unroll
        for (int r = 0; r < 4; r++) linv[qs][r] = __builtin_amdgcn_rcpf(lv[r]);
    }
    const int b_ = bh >> 4, h_ = bh & 15;
#pragma unroll
    for (int qs = 0; qs < 2; qs++)
#pragma unroll
        for (int c = 0; c < 4; c++)
#pragma unroll
            for (int r = 0; r < 4; r++) {
                const int s = q0 + wave * 32 + qs * 16 + quad * 4 + r;
                const int d = c * 16 + l16;
                ctx[((size_t)(b_ * SS + s)) * HD + h_ * DD + d] =
                    f2bf(o[qs][c][r] * linv[qs][r]);
            }
}

// ---------------- LayerNorm (row = 1024) ----------------
__global__ __launch_bounds__(256) void ln_kernel(
    const float* __restrict__ X, const float* __restrict__ g, const float* __restrict__ b,
    float* __restrict__ Y, short* __restrict__ Yb)
{
    const int row = blockIdx.x;
    const int t = threadIdx.x;
    const float4 v = *(const float4*)(X + (size_t)row * HD + t * 4);
    float s = v.x + v.y + v.z + v.w;
    float sq = v.x * v.x + v.y * v.y + v.z * v.z + v.w * v.w;
#pragma unroll
    for (int m = 1; m < 64; m <<= 1) { s += __shfl_xor(s, m); sq += __shfl_xor(sq, m); }
    __shared__ float red[8];
    const int wave = t >> 6, lane = t & 63;
    if (lane == 0) { red[wave] = s; red[4 + wave] = sq; }
    __syncthreads();
    s  = red[0] + red[1] + red[2] + red[3];
    sq = red[4] + red[5] + red[6] + red[7];
    const float mu = s * (1.f / HD);
    const float var = sq * (1.f / HD) - mu * mu;
    const float rs = rsqrtf(var + 1e-12f);
    const float4 gg = *(const float4*)(g + t * 4);
    const float4 bb = *(const float4*)(b + t * 4);
    const float y0 = (v.x - mu) * rs * gg.x + bb.x;
    const float y1 = (v.y - mu) * rs * gg.y + bb.y;
    const float y2 = (v.z - mu) * rs * gg.z + bb.z;
    const float y3 = (v.w - mu) * rs * gg.w + bb.w;
    if (Y)  { float4 o = { y0, y1, y2, y3 }; *(float4*)(Y + (size_t)row * HD + t * 4) = o; }
    if (Yb) { v4s o = { f2bf(y0), f2bf(y1), f2bf(y2), f2bf(y3) };
              *(v4s*)(Yb + (size_t)row * HD + t * 4) = o; }
}

// ---------------- launch ----------------
extern "C" void kernel_launch(void* const* d_in, const int* in_sizes, int n_in,
                              void* d_out, int out_size, void* d_ws, size_t ws_size,
                              hipStream_t stream)
{
    (void)in_sizes; (void)n_in; (void)out_size;
    const float* x   = (const float*)d_in[0];
    const float* Wq  = (const float*)d_in[1];
    const float* bq  = (const float*)d_in[2];
    const float* Wk  = (const float*)d_in[3];
    const float* bk  = (const float*)d_in[4];
    const float* Wv  = (const float*)d_in[5];
    const float* bv  = (const float*)d_in[6];
    const float* Wo  = (const float*)d_in[7];
    const float* bo  = (const float*)d_in[8];
    const float* g1  = (const float*)d_in[9];
    const float* be1 = (const float*)d_in[10];
    const float* W1  = (const float*)d_in[11];
    const float* b1  = (const float*)d_in[12];
    const float* W2  = (const float*)d_in[13];
    const float* b2  = (const float*)d_in[14];
    const float* g2  = (const float*)d_in[15];
    const float* be2 = (const float*)d_in[16];

    char* ws = (char*)d_ws;
    size_t off = 0;
    auto alloc = [&](size_t sz) { char* p = ws + off; off += sz; return p; };
    short* xb    = (short*)alloc((size_t)BS * HD * 2);
    short* WqkvT = (short*)alloc((size_t)3 * HD * HD * 2);  // [3072][1024]
    short* WoT   = (short*)alloc((size_t)HD * HD * 2);
    short* W1T   = (short*)alloc((size_t)FFF * HD * 2);
    short* W2T   = (short*)alloc((size_t)HD * FFF * 2);
    float* ropeC = (float*)alloc((size_t)SS * 32 * 4);
    float* ropeS = (float*)alloc((size_t)SS * 32 * 4);
    short* Qh    = (short*)alloc((size_t)BHN * SS * DD * 2);  // Qh,Kh contiguous
    short* Kh    = (short*)alloc((size_t)BHN * SS * DD * 2);
    short* Vt    = (short*)alloc((size_t)BHN * SS * DD * 2);  // [bh][d][s]
    short* ctx   = (short*)alloc((size_t)BS * HD * 2);
    float* ao    = (float*)alloc((size_t)BS * HD * 4);
    if (off > ws_size) return;
    short* f1 = Qh;              // alias: Qh..ctx span (64MB) dead before FFN1
    short* hb = xb;              // alias: xb dead after QKV projections
    float* f2 = (float*)d_out;   // FFN2 output staged in d_out, LN2 in-place

    // Q pre-scale: 1/sqrt(D) * log2(e) so attention uses exp2 directly
    const float qsc = 0.125f * 1.4426950408889634f;

    cast_bf16<<<BS * HD / 1024, 256, 0, stream>>>(x, xb, BS * HD);
    rope_tab<<<SS * 32 / 256, 256, 0, stream>>>(ropeC, ropeS);
    transW_all<<<3072, 256, 0, stream>>>(Wq, Wk, Wv, Wo, W1, W2,
                                         WqkvT, WoT, W1T, W2T);

    // fused QKV: N = 3072 -> Qh/Kh (head layout) + Vt (transposed) directly
    gemm128<0><<<dim3(64, 24), 256, 0, stream>>>(xb, WqkvT, bq, bk, bv, Qh, Vt,
                                                 nullptr, ropeC, ropeS, BS, 3 * HD, HD, qsc);
    attn_kernel<<<dim3(64, SS / 128), 256, 0, stream>>>(Qh, Kh, Vt, ctx);
    gemm128<2><<<dim3(64, 8), 256, 0, stream>>>(ctx, WoT, bo, nullptr, nullptr, ao,
                                                nullptr, x, nullptr, nullptr, BS, HD, HD, 1.0f);
    ln_kernel<<<BS, 256, 0, stream>>>(ao, g1, be1, nullptr, hb);
    gemm128<3><<<dim3(64, 32), 256, 0, stream>>>(hb, W1T, b1, nullptr, nullptr, f1,
                                                 nullptr, nullptr, nullptr, nullptr, BS, FFF, HD, 1.0f);
    gemm128<4><<<dim3(64, 8), 256, 0, stream>>>(f1, W2T, b2, nullptr, nullptr, f2,
                                                nullptr, hb, nullptr, nullptr, BS, HD, FFF, 1.0f);
    ln_kernel<<<BS, 256, 0, stream>>>(f2, g2, be2, (float*)d_out, nullptr);
}

// Round 9
// 503.256 us; speedup vs baseline: 1.0952x; 1.0952x over previous
//
#include <hip/hip_runtime.h>

#define BB   4
#define SS   2048
#define HD   1024
#define NHH  16
#define DD   64
#define FFF  4096
#define BS   (BB*SS)   // 8192 rows
#define BHN  (BB*NHH)  // 64 (b,h) pairs

typedef __attribute__((ext_vector_type(8))) short v8s;   // 8 bf16 (4 VGPR)
typedef __attribute__((ext_vector_type(4))) short v4s;
typedef __attribute__((ext_vector_type(4))) float v4f;

__device__ __forceinline__ short f2bf(float f) {
    union { float f; unsigned u; } v; v.f = f;
    unsigned r = (v.u + 0x7fffu + ((v.u >> 16) & 1u)) >> 16;
    return (short)r;
}
__device__ __forceinline__ float bf2f(short s) {
    union { unsigned u; float f; } v; v.u = ((unsigned)(unsigned short)s) << 16;
    return v.f;
}
// packed bf16 truncation of two floats: 1 VALU op (v_perm_b32)
__device__ __forceinline__ unsigned pktrunc(float lo, float hi) {
    return __builtin_amdgcn_perm(__builtin_bit_cast(unsigned, hi),
                                 __builtin_bit_cast(unsigned, lo), 0x07060302u);
}
__device__ __forceinline__ v4f mfma16(v8s a, v8s b, v4f c) {
    return __builtin_amdgcn_mfma_f32_16x16x32_bf16(a, b, c, 0, 0, 0);
}
// async global->LDS, 16B per lane; LDS dest = wave-uniform base + lane*16
__device__ __forceinline__ void cp16(void* lds, const void* g) {
    __builtin_amdgcn_global_load_lds(
        (const __attribute__((address_space(1))) unsigned*)g,
        (__attribute__((address_space(3))) unsigned*)lds, 16, 0, 0);
}

// ---------------- fused prep kernel (cast + rope table + 6 transposes) ------
// flat grid: [0,8192) cast_bf16, [8192,8448) rope, [8448,11520) transW 64x64.
__global__ __launch_bounds__(256) void prep_all(
    const float* __restrict__ x, short* __restrict__ xb,
    float* __restrict__ ropeC, float* __restrict__ ropeS,
    const float* __restrict__ Wq, const float* __restrict__ Wk,
    const float* __restrict__ Wv, const float* __restrict__ Wo,
    const float* __restrict__ W1, const float* __restrict__ W2,
    short* __restrict__ WqkvT, short* __restrict__ WoT,
    short* __restrict__ W1T, short* __restrict__ W2T)
{
    __shared__ float T[64][65];
    const int t = threadIdx.x;
    const int id = blockIdx.x;
    if (id < 8192) {                       // bf16 cast of x
        const int i = (id * 256 + t) * 4;
        const float4 v = *(const float4*)(x + i);
        v4s o = { f2bf(v.x), f2bf(v.y), f2bf(v.z), f2bf(v.w) };
        *(v4s*)(xb + i) = o;
        return;
    }
    if (id < 8448) {                       // rope table
        const int i = (id - 8192) * 256 + t;   // < SS*32
        const int s = i >> 5, di = i & 31;
        const float inv = powf(10000.f, -(float)(2 * di) * (1.f / 64.f));
        const float a = (float)s * inv;
        ropeC[i] = cosf(a);
        ropeS[i] = sinf(a);
        return;
    }
    const int wid = id - 8448;
    const float* W; short* WT; int K, N, bx, by;
    if (wid < 768) {            // Wq,Wk,Wv -> WqkvT (256 blocks each, 16x16)
        const int m = wid >> 8;
        W = (m == 0) ? Wq : (m == 1) ? Wk : Wv;
        WT = WqkvT + (size_t)m * HD * HD;
        K = HD; N = HD; const int r = wid & 255; bx = r & 15; by = r >> 4;
    } else if (wid < 1024) {    // Wo (16x16)
        W = Wo; WT = WoT; K = HD; N = HD;
        const int r = wid - 768; bx = r & 15; by = r >> 4;
    } else if (wid < 2048) {    // W1: K=1024, N=4096 (64x16)
        W = W1; WT = W1T; K = HD; N = FFF;
        const int r = wid - 1024; bx = r & 63; by = r >> 6;
    } else {                    // W2: K=4096, N=1024 (16x64)
        W = W2; WT = W2T; K = FFF; N = HD;
        const int r = wid - 2048; bx = r & 15; by = r >> 4;
    }
    const int r0 = by * 64, c0 = bx * 64;
#pragma unroll
    for (int i = 0; i < 4; i++) {
        const int lin = t + 256 * i;
        const int r = lin >> 4, c = (lin & 15) * 4;
        const float4 v = *(const float4*)(W + (size_t)(r0 + r) * N + c0 + c);
        T[r][c] = v.x; T[r][c+1] = v.y; T[r][c+2] = v.z; T[r][c+3] = v.w;
    }
    __syncthreads();
#pragma unroll
    for (int i = 0; i < 4; i++) {
        const int lin = t + 256 * i;
        const int n = lin >> 4, k = (lin & 15) * 4;
        v4s o = { f2bf(T[k][n]), f2bf(T[k+1][n]), f2bf(T[k+2][n]), f2bf(T[k+3][n]) };
        *(v4s*)(WT + (size_t)(c0 + n) * K + r0 + k) = o;
    }
}

// ---------------- GEMM 128x128, BK=64, dbuf (R6-proven loop) ----------------
// + LDS-repacked COALESCED epilogues:
//   main loop identical to R6 (92 us FFN1). After the final barrier the 64 KB
//   LDS is dead -> stage C there, re-read as row chunks, store v8s/float4.
//   R8 bug (quarter-coverage in EPI2/4 write-back: c4<4 instead of c4<16)
//   fixed here — 4096 float4 chunks = 16 iters x 256 threads.
// EPI 0: fused QKV (Q scale+rope, K rope -> head layout; V col-major staged,
//        stored transposed [bh][d][s]).  EPI 3: bf16 GELU row-major.
// EPI 2: fp32 out + fp32 residual.      EPI 4: fp32 out + bf16 residual.

template <int EPI>
__global__ __launch_bounds__(256, 2) void gemm128(
    const short* __restrict__ A, const short* __restrict__ Bt,
    const float* __restrict__ bias, const float* __restrict__ bias2,
    const float* __restrict__ bias3, void* __restrict__ out,
    void* __restrict__ out2, const void* __restrict__ resid,
    const float* __restrict__ ropeC, const float* __restrict__ ropeS,
    int M, int N, int K, float oscale)
{
    __shared__ short sh[32768];          // 64 KB: A dbuf | B dbuf; epilogue stg
    const int tid = threadIdx.x;
    const int wave = tid >> 6, lane = tid & 63;
    const int quad = lane >> 4, l16 = lane & 15;
    const int wm = wave & 1, wn = wave >> 1;
    const int m0 = blockIdx.x * 128, n0 = blockIdx.y * 128;

    v4f acc[4][4];
#pragma unroll
    for (int i = 0; i < 4; i++)
#pragma unroll
        for (int j = 0; j < 4; j++) { v4f z = {0.f, 0.f, 0.f, 0.f}; acc[i][j] = z; }

    const int r8 = lane >> 3;              // row within 8
    const int g8 = (lane & 7) ^ r8;        // swizzled source chunk (of 8)
    const short* Asrc = A  + (size_t)(m0 + wave * 32 + r8) * K + g8 * 8;
    const short* Bsrc = Bt + (size_t)(n0 + wave * 32 + r8) * K + g8 * 8;
    const int wofs = wave * 2048;
    const int xsw = l16 & 7;

    auto stage = [&](int buf, int kofs) {
        short* Ad = sh + buf * 8192 + wofs;
        short* Bd = sh + 16384 + buf * 8192 + wofs;
#pragma unroll
        for (int s = 0; s < 4; s++) {
            cp16(Ad + s * 512, Asrc + (size_t)(s * 8) * K + kofs);
            cp16(Bd + s * 512, Bsrc + (size_t)(s * 8) * K + kofs);
        }
    };

    stage(0, 0);
    __syncthreads();           // implicit vmcnt(0): tile 0 resident

    int cur = 0;
    for (int k0 = 0; k0 < K; k0 += 64) {
        if (k0 + 64 < K) stage(cur ^ 1, k0 + 64);   // issue next tile FIRST
#pragma unroll
        for (int ks = 0; ks < 2; ks++) {
            v8s af[4], bfr[4];
#pragma unroll
            for (int i = 0; i < 4; i++)
                af[i] = *(const v8s*)(&sh[cur * 8192 + (wm * 64 + i * 16 + l16) * 64
                                          + ((ks * 4 + quad) ^ xsw) * 8]);
#pragma unroll
            for (int j = 0; j < 4; j++)
                bfr[j] = *(const v8s*)(&sh[16384 + cur * 8192 + (wn * 64 + j * 16 + l16) * 64
                                           + ((ks * 4 + quad) ^ xsw) * 8]);
#pragma unroll
            for (int i = 0; i < 4; i++)
#pragma unroll
                for (int j = 0; j < 4; j++)
                    acc[i][j] = mfma16(af[i], bfr[j], acc[i][j]);
        }
        __syncthreads();       // all ds_reads drained; buf free for overwrite
        cur ^= 1;
    }
    // loop ended with a barrier: sh is dead -> reuse as epilogue staging.

    if constexpr (EPI == 0) {
        const int h = n0 >> 10;            // block-uniform: 0=Q, 1=K, 2=V
        short* stg = sh;                   // [128][136] bf16 (pitch-padded)
        if (h == 2) {
            // V: col-major staging [lc][row]; v4s = 4 consecutive rows (s)
#pragma unroll
            for (int j = 0; j < 4; j++) {
                const int lc = wn * 64 + j * 16 + l16;
                const float bval = bias3[(n0 + lc) & 1023];
#pragma unroll
                for (int i = 0; i < 4; i++) {
                    const int row0 = wm * 64 + i * 16 + quad * 4;
                    v4s ov = { f2bf(acc[i][j][0] + bval), f2bf(acc[i][j][1] + bval),
                               f2bf(acc[i][j][2] + bval), f2bf(acc[i][j][3] + bval) };
                    *(v4s*)(stg + lc * 136 + row0) = ov;
                }
            }
            __syncthreads();
#pragma unroll
            for (int c8 = 0; c8 < 8; ++c8) {
                const int lin = c8 * 256 + tid;
                const int lc = lin >> 4, ch = lin & 15;
                const int gcol = n0 + lc;
                const int hh = (gcol >> 6) & 15, d = gcol & 63;
                const int grow = m0 + ch * 8;
                const int b_ = grow >> 11, s0 = grow & (SS - 1);
                const v8s v = *(const v8s*)(stg + lc * 136 + ch * 8);
                *(v8s*)((short*)out2 + ((size_t)(b_ * NHH + hh) * DD + d) * SS + s0) = v;
            }
        } else {
            const float* bp = (h == 0) ? bias : bias2;
#pragma unroll
            for (int j = 0; j < 4; j++) {
                const int lc = wn * 64 + j * 16 + l16;
                const int col = n0 + lc;
                const float bval = bp[col & 1023];
                const int d = col & 63;
#pragma unroll
                for (int i = 0; i < 4; i++) {
#pragma unroll
                    for (int r = 0; r < 4; r++) {
                        const int row = wm * 64 + i * 16 + quad * 4 + r;
                        float v = acc[i][j][r] + bval;
                        if (h == 0) v *= oscale;
                        const int s = (m0 + row) & (SS - 1);
                        const float cv = ropeC[s * 32 + (d >> 1)];
                        const float sv = ropeS[s * 32 + (d >> 1)];
                        const float partner = __shfl_xor(v, 1);
                        const float o = (d & 1) ? fmaf(v, cv, partner * sv)
                                                : fmaf(v, cv, -partner * sv);
                        stg[row * 136 + lc] = f2bf(o);
                    }
                }
            }
            __syncthreads();
            const size_t hbase = (size_t)h * (BHN * SS * DD);
#pragma unroll
            for (int c8 = 0; c8 < 8; ++c8) {
                const int lin = c8 * 256 + tid;
                const int row = lin >> 4, ch = lin & 15;
                const int grow = m0 + row;
                const int b_ = grow >> 11, s = grow & (SS - 1);
                const int gcol = n0 + ch * 8;
                const int hh = (gcol >> 6) & 15, d = gcol & 63;
                const v8s v = *(const v8s*)(stg + row * 136 + ch * 8);
                *(v8s*)((short*)out + hbase
                        + (((size_t)(b_ * NHH + hh)) * SS + s) * DD + d) = v;
            }
        }
    } else if constexpr (EPI == 3) {
        short* stg = sh;                   // [128][136] bf16
#pragma unroll
        for (int j = 0; j < 4; j++) {
            const int lc = wn * 64 + j * 16 + l16;
            const float bval = bias[n0 + lc];
#pragma unroll
            for (int i = 0; i < 4; i++) {
#pragma unroll
                for (int r = 0; r < 4; r++) {
                    const int row = wm * 64 + i * 16 + quad * 4 + r;
                    float v = acc[i][j][r] + bval;
                    // gelu(v) = v * sigmoid(2u), u = 0.7978845608*(v + 0.044715 v^3)
                    const float tq = v * v;
                    const float u = v * fmaf(0.035677408136f, tq, 0.7978845608028654f);
                    const float e = __builtin_amdgcn_exp2f(-2.8853900817779268f * u);
                    const float g = v * __builtin_amdgcn_rcpf(1.f + e);
                    stg[row * 136 + lc] = f2bf(g);
                }
            }
        }
        __syncthreads();
#pragma unroll
        for (int c8 = 0; c8 < 8; ++c8) {
            const int lin = c8 * 256 + tid;
            const int row = lin >> 4, ch = lin & 15;
            const v8s v = *(const v8s*)(stg + row * 136 + ch * 8);
            *(v8s*)((short*)out + (size_t)(m0 + row) * N + n0 + ch * 8) = v;
        }
    } else {
        float* stg = (float*)sh;           // [128][128] fp32 = 64 KB exactly
#pragma unroll
        for (int j = 0; j < 4; j++) {
            const int lc = wn * 64 + j * 16 + l16;
            const float bval = bias[n0 + lc];
#pragma unroll
            for (int i = 0; i < 4; i++) {
#pragma unroll
                for (int r = 0; r < 4; r++) {
                    const int row = wm * 64 + i * 16 + quad * 4 + r;
                    stg[row * 128 + lc] = acc[i][j][r] + bval;
                }
            }
        }
        __syncthreads();
        // 128x128 fp32 tile = 4096 float4 chunks = 16 iters x 256 threads
#pragma unroll
        for (int c4 = 0; c4 < 16; ++c4) {
            const int lin = c4 * 256 + tid;
            const int row = lin >> 5, ch = lin & 31;
            float4 v = *(const float4*)(stg + row * 128 + ch * 4);
            const size_t gi = (size_t)(m0 + row) * N + n0 + ch * 4;
            if constexpr (EPI == 2) {
                const float4 rv = *(const float4*)((const float*)resid + gi);
                v.x += rv.x; v.y += rv.y; v.z += rv.z; v.w += rv.w;
            } else {
                const v4s rb = *(const v4s*)((const short*)resid + gi);
                v.x += bf2f(rb[0]); v.y += bf2f(rb[1]);
                v.z += bf2f(rb[2]); v.w += bf2f(rb[3]);
            }
            *(float4*)((float*)out + gi) = v;
        }
    }
}

// ---------------- flash attention (single-buffered, R0/R6-proven) -----------
// grid (64 bh fast, SS/128 q-tiles); block 256 = 4 waves; wave owns 32 q rows.
// S^T formulation; no max-subtraction (scores bounded); Q pre-scaled by
// 0.125*log2e in the fused-QKV epilogue, so P = exp2(score).
// R5 lesson: double-buffering K/V cut occupancy and regressed; keep TLP.
__global__ __launch_bounds__(256, 4) void attn_kernel(
    const short* __restrict__ Qh, const short* __restrict__ Kh,
    const short* __restrict__ Vt, short* __restrict__ ctx)
{
    __shared__ short Ks[64 * 64];     // [key][d-chunk swizzled]
    __shared__ short Vs[64 * 64];     // [d][key-chunk swizzled]
    __shared__ short Ps[4][16 * 88];  // per-wave P buffer [q][key], pitch 88
    __shared__ float Li[4][32];
    const int bh = blockIdx.x, q0 = blockIdx.y * 128;
    const int t = threadIdx.x, wave = t >> 6, lane = t & 63;
    const int quad = lane >> 4, l16 = lane & 15;

    // Q fragments (B-operand): lane = query q0 + wave*32 + qs*16 + l16
    const short* qp = Qh + ((size_t)bh * SS + q0 + wave * 32 + l16) * DD;
    v8s bq[2][2];
    bq[0][0] = *(const v8s*)(qp + quad * 8);
    bq[0][1] = *(const v8s*)(qp + 32 + quad * 8);
    bq[1][0] = *(const v8s*)(qp + (size_t)16 * DD + quad * 8);
    bq[1][1] = *(const v8s*)(qp + (size_t)16 * DD + 32 + quad * 8);

    v4f o[2][4];
#pragma unroll
    for (int qs = 0; qs < 2; qs++)
#pragma unroll
        for (int c = 0; c < 4; c++) { v4f z = {0.f, 0.f, 0.f, 0.f}; o[qs][c] = z; }
    float li[2] = {0.f, 0.f};

    const short* Kb = Kh + (size_t)bh * SS * DD;
    const short* Vb = Vt + (size_t)bh * DD * SS;
    const int r8 = lane >> 3;                      // row within 8
    const int g8 = (lane & 7) ^ (r8 & 7);          // swizzled source chunk
    short* Psw = (short*)Ps[wave];
    const int xsw = l16 & 7;                       // fragment-read swizzle

    for (int kt = 0; kt < SS; kt += 64) {
        __syncthreads();
        cp16(Ks + wave * 1024,       Kb + (size_t)(kt + wave * 16 + r8) * DD + g8 * 8);
        cp16(Ks + wave * 1024 + 512, Kb + (size_t)(kt + wave * 16 + 8 + r8) * DD + g8 * 8);
        cp16(Vs + wave * 1024,       Vb + (size_t)(wave * 16 + r8) * SS + kt + g8 * 8);
        cp16(Vs + wave * 1024 + 512, Vb + (size_t)(wave * 16 + 8 + r8) * SS + kt + g8 * 8);
        __syncthreads();

        // S^T = K Q^T : D[m=key][n=q]; sc[qs][c][r] = score(key=c*16+quad*4+r, q)
        v4f sc[2][4];
#pragma unroll
        for (int c = 0; c < 4; c++) {
            const v8s k0f = *(const v8s*)(Ks + (c * 16 + l16) * 64 + ((quad    ) ^ xsw) * 8);
            const v8s k1f = *(const v8s*)(Ks + (c * 16 + l16) * 64 + ((quad + 4) ^ xsw) * 8);
#pragma unroll
            for (int qs = 0; qs < 2; qs++) {
                v4f z = {0.f, 0.f, 0.f, 0.f};
                z = mfma16(k0f, bq[qs][0], z);
                z = mfma16(k1f, bq[qs][1], z);
                sc[qs][c] = z;
            }
        }

        // softmax (no max): p = exp2(score); li in fp32; P -> LDS via packed
        // bf16 TRUNCATION (v_perm_b32, 1 op / 2 elems) + ds_write_b64
        v8s pa[2][2];
#pragma unroll
        for (int qs = 0; qs < 2; qs++) {
            float lp = 0.f;
#pragma unroll
            for (int c = 0; c < 4; c++) {
#pragma unroll
                for (int r = 0; r < 4; r++) {
                    const float p = __builtin_amdgcn_exp2f(sc[qs][c][r]);
                    sc[qs][c][r] = p;
                    lp += p;
                }
            }
            li[qs] += lp;
            short* pw = Psw + l16 * 88;
#pragma unroll
            for (int c = 0; c < 4; c++) {
                uint2 w;
                w.x = pktrunc(sc[qs][c][0], sc[qs][c][1]);
                w.y = pktrunc(sc[qs][c][2], sc[qs][c][3]);
                *(uint2*)(pw + c * 16 + quad * 4) = w;
            }
            pa[qs][0] = *(const v8s*)(Psw + l16 * 88 + quad * 8);
            pa[qs][1] = *(const v8s*)(Psw + l16 * 88 + 32 + quad * 8);
        }

        // O += P V : A=P[q][key], B=Vs[d][key]
#pragma unroll
        for (int c = 0; c < 4; c++) {
            const v8s v0f = *(const v8s*)(Vs + (c * 16 + l16) * 64 + ((quad    ) ^ xsw) * 8);
            const v8s v1f = *(const v8s*)(Vs + (c * 16 + l16) * 64 + ((quad + 4) ^ xsw) * 8);
#pragma unroll
            for (int qs = 0; qs < 2; qs++) {
                o[qs][c] = mfma16(pa[qs][0], v0f, o[qs][c]);
                o[qs][c] = mfma16(pa[qs][1], v1f, o[qs][c]);
            }
        }
    }

    // finalize li (cross-quad, once) and divide
    float linv[2][4];
#pragma unroll
    for (int qs = 0; qs < 2; qs++) {
        float lf = li[qs];
        lf += __shfl_xor(lf, 16);
        lf += __shfl_xor(lf, 32);
        if (quad == 0) Li[wave][qs * 16 + l16] = lf;
    }
    __syncthreads();
#pragma unroll
    for (int qs = 0; qs < 2; qs++) {
        const v4f lv = *(const v4f*)(&Li[wave][qs * 16 + quad * 4]);
#pragma unroll
        for (int r = 0; r < 4; r++) linv[qs][r] = __builtin_amdgcn_rcpf(lv[r]);
    }
    const int b_ = bh >> 4, h_ = bh & 15;
#pragma unroll
    for (int qs = 0; qs < 2; qs++)
#pragma unroll
        for (int c = 0; c < 4; c++)
#pragma unroll
            for (int r = 0; r < 4; r++) {
                const int s = q0 + wave * 32 + qs * 16 + quad * 4 + r;
                const int d = c * 16 + l16;
                ctx[((size_t)(b_ * SS + s)) * HD + h_ * DD + d] =
                    f2bf(o[qs][c][r] * linv[qs][r]);
            }
}

// ---------------- LayerNorm (row = 1024) ----------------
__global__ __launch_bounds__(256) void ln_kernel(
    const float* __restrict__ X, const float* __restrict__ g, const float* __restrict__ b,
    float* __restrict__ Y, short* __restrict__ Yb)
{
    const int row = blockIdx.x;
    const int t = threadIdx.x;
    const float4 v = *(const float4*)(X + (size_t)row * HD + t * 4);
    float s = v.x + v.y + v.z + v.w;
    float sq = v.x * v.x + v.y * v.y + v.z * v.z + v.w * v.w;
#pragma unroll
    for (int m = 1; m < 64; m <<= 1) { s += __shfl_xor(s, m); sq += __shfl_xor(sq, m); }
    __shared__ float red[8];
    const int wave = t >> 6, lane = t & 63;
    if (lane == 0) { red[wave] = s; red[4 + wave] = sq; }
    __syncthreads();
    s  = red[0] + red[1] + red[2] + red[3];
    sq = red[4] + red[5] + red[6] + red[7];
    const float mu = s * (1.f / HD);
    const float var = sq * (1.f / HD) - mu * mu;
    const float rs = rsqrtf(var + 1e-12f);
    const float4 gg = *(const float4*)(g + t * 4);
    const float4 bb = *(const float4*)(b + t * 4);
    const float y0 = (v.x - mu) * rs * gg.x + bb.x;
    const float y1 = (v.y - mu) * rs * gg.y + bb.y;
    const float y2 = (v.z - mu) * rs * gg.z + bb.z;
    const float y3 = (v.w - mu) * rs * gg.w + bb.w;
    if (Y)  { float4 o = { y0, y1, y2, y3 }; *(float4*)(Y + (size_t)row * HD + t * 4) = o; }
    if (Yb) { v4s o = { f2bf(y0), f2bf(y1), f2bf(y2), f2bf(y3) };
              *(v4s*)(Yb + (size_t)row * HD + t * 4) = o; }
}

// ---------------- launch ----------------
extern "C" void kernel_launch(void* const* d_in, const int* in_sizes, int n_in,
                              void* d_out, int out_size, void* d_ws, size_t ws_size,
                              hipStream_t stream)
{
    (void)in_sizes; (void)n_in; (void)out_size;
    const float* x   = (const float*)d_in[0];
    const float* Wq  = (const float*)d_in[1];
    const float* bq  = (const float*)d_in[2];
    const float* Wk  = (const float*)d_in[3];
    const float* bk  = (const float*)d_in[4];
    const float* Wv  = (const float*)d_in[5];
    const float* bv  = (const float*)d_in[6];
    const float* Wo  = (const float*)d_in[7];
    const float* bo  = (const float*)d_in[8];
    const float* g1  = (const float*)d_in[9];
    const float* be1 = (const float*)d_in[10];
    const float* W1  = (const float*)d_in[11];
    const float* b1  = (const float*)d_in[12];
    const float* W2  = (const float*)d_in[13];
    const float* b2  = (const float*)d_in[14];
    const float* g2  = (const float*)d_in[15];
    const float* be2 = (const float*)d_in[16];

    char* ws = (char*)d_ws;
    size_t off = 0;
    auto alloc = [&](size_t sz) { char* p = ws + off; off += sz; return p; };
    short* xb    = (short*)alloc((size_t)BS * HD * 2);
    short* WqkvT = (short*)alloc((size_t)3 * HD * HD * 2);  // [3072][1024]
    short* WoT   = (short*)alloc((size_t)HD * HD * 2);
    short* W1T   = (short*)alloc((size_t)FFF * HD * 2);
    short* W2T   = (short*)alloc((size_t)HD * FFF * 2);
    float* ropeC = (float*)alloc((size_t)SS * 32 * 4);
    float* ropeS = (float*)alloc((size_t)SS * 32 * 4);
    short* Qh    = (short*)alloc((size_t)BHN * SS * DD * 2);  // Qh,Kh contiguous
    short* Kh    = (short*)alloc((size_t)BHN * SS * DD * 2);
    short* Vt    = (short*)alloc((size_t)BHN * SS * DD * 2);  // [bh][d][s]
    short* ctx   = (short*)alloc((size_t)BS * HD * 2);
    float* ao    = (float*)alloc((size_t)BS * HD * 4);
    if (off > ws_size) return;
    short* f1 = Qh;              // alias: Qh..ctx span (64MB) dead before FFN1
    short* hb = xb;              // alias: xb dead after QKV projections
    float* f2 = (float*)d_out;   // FFN2 output staged in d_out, LN2 in-place

    // Q pre-scale: 1/sqrt(D) * log2(e) so attention uses exp2 directly
    const float qsc = 0.125f * 1.4426950408889634f;

    prep_all<<<11520, 256, 0, stream>>>(x, xb, ropeC, ropeS,
                                        Wq, Wk, Wv, Wo, W1, W2,
                                        WqkvT, WoT, W1T, W2T);

    // fused QKV: N = 3072 -> Qh/Kh (head layout) + Vt (transposed) directly
    gemm128<0><<<dim3(64, 24), 256, 0, stream>>>(xb, WqkvT, bq, bk, bv, Qh, Vt,
                                                 nullptr, ropeC, ropeS, BS, 3 * HD, HD, qsc);
    attn_kernel<<<dim3(64, SS / 128), 256, 0, stream>>>(Qh, Kh, Vt, ctx);
    gemm128<2><<<dim3(64, 8), 256, 0, stream>>>(ctx, WoT, bo, nullptr, nullptr, ao,
                                                nullptr, x, nullptr, nullptr, BS, HD, HD, 1.0f);
    ln_kernel<<<BS, 256, 0, stream>>>(ao, g1, be1, nullptr, hb);
    gemm128<3><<<dim3(64, 32), 256, 0, stream>>>(hb, W1T, b1, nullptr, nullptr, f1,
                                                 nullptr, nullptr, nullptr, nullptr, BS, FFF, HD, 1.0f);
    gemm128<4><<<dim3(64, 8), 256, 0, stream>>>(f1, W2T, b2, nullptr, nullptr, f2,
                                                nullptr, hb, nullptr, nullptr, BS, HD, FFF, 1.0f);
    ln_kernel<<<BS, 256, 0, stream>>>(f2, g2, be2, (float*)d_out, nullptr);
}

// Round 10
// 476.130 us; speedup vs baseline: 1.1576x; 1.0570x over previous
//
#include <hip/hip_runtime.h>

#define BB   4
#define SS   2048
#define HD   1024
#define NHH  16
#define DD   64
#define FFF  4096
#define BS   (BB*SS)   // 8192 rows
#define BHN  (BB*NHH)  // 64 (b,h) pairs

typedef __attribute__((ext_vector_type(8))) short v8s;   // 8 bf16 (4 VGPR)
typedef __attribute__((ext_vector_type(4))) short v4s;
typedef __attribute__((ext_vector_type(4))) float v4f;

__device__ __forceinline__ short f2bf(float f) {
    union { float f; unsigned u; } v; v.f = f;
    unsigned r = (v.u + 0x7fffu + ((v.u >> 16) & 1u)) >> 16;
    return (short)r;
}
__device__ __forceinline__ float bf2f(short s) {
    union { unsigned u; float f; } v; v.u = ((unsigned)(unsigned short)s) << 16;
    return v.f;
}
// packed bf16 truncation of two floats: 1 VALU op (v_perm_b32)
__device__ __forceinline__ unsigned pktrunc(float lo, float hi) {
    return __builtin_amdgcn_perm(__builtin_bit_cast(unsigned, hi),
                                 __builtin_bit_cast(unsigned, lo), 0x07060302u);
}
__device__ __forceinline__ v4f mfma16(v8s a, v8s b, v4f c) {
    return __builtin_amdgcn_mfma_f32_16x16x32_bf16(a, b, c, 0, 0, 0);
}
// async global->LDS, 16B per lane; LDS dest = wave-uniform base + lane*16
__device__ __forceinline__ void cp16(void* lds, const void* g) {
    __builtin_amdgcn_global_load_lds(
        (const __attribute__((address_space(1))) unsigned*)g,
        (__attribute__((address_space(3))) unsigned*)lds, 16, 0, 0);
}

// ---------------- fused prep kernel (cast + rope table + 6 transposes) ------
// flat grid: [0,8192) cast_bf16, [8192,8448) rope, [8448,11520) transW 64x64.
__global__ __launch_bounds__(256) void prep_all(
    const float* __restrict__ x, short* __restrict__ xb,
    float* __restrict__ ropeC, float* __restrict__ ropeS,
    const float* __restrict__ Wq, const float* __restrict__ Wk,
    const float* __restrict__ Wv, const float* __restrict__ Wo,
    const float* __restrict__ W1, const float* __restrict__ W2,
    short* __restrict__ WqkvT, short* __restrict__ WoT,
    short* __restrict__ W1T, short* __restrict__ W2T)
{
    __shared__ float T[64][65];
    const int t = threadIdx.x;
    const int id = blockIdx.x;
    if (id < 8192) {                       // bf16 cast of x
        const int i = (id * 256 + t) * 4;
        const float4 v = *(const float4*)(x + i);
        v4s o = { f2bf(v.x), f2bf(v.y), f2bf(v.z), f2bf(v.w) };
        *(v4s*)(xb + i) = o;
        return;
    }
    if (id < 8448) {                       // rope table
        const int i = (id - 8192) * 256 + t;   // < SS*32
        const int s = i >> 5, di = i & 31;
        const float inv = powf(10000.f, -(float)(2 * di) * (1.f / 64.f));
        const float a = (float)s * inv;
        ropeC[i] = cosf(a);
        ropeS[i] = sinf(a);
        return;
    }
    const int wid = id - 8448;
    const float* W; short* WT; int K, N, bx, by;
    if (wid < 768) {            // Wq,Wk,Wv -> WqkvT (256 blocks each, 16x16)
        const int m = wid >> 8;
        W = (m == 0) ? Wq : (m == 1) ? Wk : Wv;
        WT = WqkvT + (size_t)m * HD * HD;
        K = HD; N = HD; const int r = wid & 255; bx = r & 15; by = r >> 4;
    } else if (wid < 1024) {    // Wo (16x16)
        W = Wo; WT = WoT; K = HD; N = HD;
        const int r = wid - 768; bx = r & 15; by = r >> 4;
    } else if (wid < 2048) {    // W1: K=1024, N=4096 (64x16)
        W = W1; WT = W1T; K = HD; N = FFF;
        const int r = wid - 1024; bx = r & 63; by = r >> 6;
    } else {                    // W2: K=4096, N=1024 (16x64)
        W = W2; WT = W2T; K = FFF; N = HD;
        const int r = wid - 2048; bx = r & 15; by = r >> 4;
    }
    const int r0 = by * 64, c0 = bx * 64;
#pragma unroll
    for (int i = 0; i < 4; i++) {
        const int lin = t + 256 * i;
        const int r = lin >> 4, c = (lin & 15) * 4;
        const float4 v = *(const float4*)(W + (size_t)(r0 + r) * N + c0 + c);
        T[r][c] = v.x; T[r][c+1] = v.y; T[r][c+2] = v.z; T[r][c+3] = v.w;
    }
    __syncthreads();
#pragma unroll
    for (int i = 0; i < 4; i++) {
        const int lin = t + 256 * i;
        const int n = lin >> 4, k = (lin & 15) * 4;
        v4s o = { f2bf(T[k][n]), f2bf(T[k+1][n]), f2bf(T[k+2][n]), f2bf(T[k+3][n]) };
        *(v4s*)(WT + (size_t)(c0 + n) * K + r0 + k) = o;
    }
}

// ---------------- GEMM 128x128, BK=64, dbuf (R6-proven loop) ----------------
// + LDS-repacked coalesced epilogues (R9) + XCD-aware block swizzle (R10).
// XCD swizzle: physical bid p lands on XCD p%8 (round-robin). Remap
//   p = xcd + 8t  ->  mb = xcd*8 + (t&7), nb = t>>3        (needs 64 m-blocks)
// so each XCD owns an 8-m-block stripe (2 MB of A-panels, L2-resident) and
// walks all n reusing A from its private L2 instead of L3 (T1, +10% m192).
// EPI 0: fused QKV (Q scale+rope, K rope -> head layout; V transposed)
// EPI 2: fp32 out + fp32 residual      EPI 3: bf16 GELU
// EPI 4: fp32 out + bf16 residual

template <int EPI>
__global__ __launch_bounds__(256, 2) void gemm128(
    const short* __restrict__ A, const short* __restrict__ Bt,
    const float* __restrict__ bias, const float* __restrict__ bias2,
    const float* __restrict__ bias3, void* __restrict__ out,
    void* __restrict__ out2, const void* __restrict__ resid,
    const float* __restrict__ ropeC, const float* __restrict__ ropeS,
    int M, int N, int K, float oscale)
{
    __shared__ short sh[32768];          // 64 KB: A dbuf | B dbuf; epilogue stg
    const int tid = threadIdx.x;
    const int wave = tid >> 6, lane = tid & 63;
    const int quad = lane >> 4, l16 = lane & 15;
    const int wm = wave & 1, wn = wave >> 1;
    // XCD-aware remap (grid is (64, N/128); 64 m-blocks for all our shapes)
    const int flat = blockIdx.x + (blockIdx.y << 6);
    const int xcd = flat & 7, tt = flat >> 3;
    const int m0 = ((xcd << 3) + (tt & 7)) << 7;
    const int n0 = (tt >> 3) << 7;

    v4f acc[4][4];
#pragma unroll
    for (int i = 0; i < 4; i++)
#pragma unroll
        for (int j = 0; j < 4; j++) { v4f z = {0.f, 0.f, 0.f, 0.f}; acc[i][j] = z; }

    const int r8 = lane >> 3;              // row within 8
    const int g8 = (lane & 7) ^ r8;        // swizzled source chunk (of 8)
    const short* Asrc = A  + (size_t)(m0 + wave * 32 + r8) * K + g8 * 8;
    const short* Bsrc = Bt + (size_t)(n0 + wave * 32 + r8) * K + g8 * 8;
    const int wofs = wave * 2048;
    const int xsw = l16 & 7;

    auto stage = [&](int buf, int kofs) {
        short* Ad = sh + buf * 8192 + wofs;
        short* Bd = sh + 16384 + buf * 8192 + wofs;
#pragma unroll
        for (int s = 0; s < 4; s++) {
            cp16(Ad + s * 512, Asrc + (size_t)(s * 8) * K + kofs);
            cp16(Bd + s * 512, Bsrc + (size_t)(s * 8) * K + kofs);
        }
    };

    stage(0, 0);
    __syncthreads();           // implicit vmcnt(0): tile 0 resident

    int cur = 0;
    for (int k0 = 0; k0 < K; k0 += 64) {
        if (k0 + 64 < K) stage(cur ^ 1, k0 + 64);   // issue next tile FIRST
#pragma unroll
        for (int ks = 0; ks < 2; ks++) {
            v8s af[4], bfr[4];
#pragma unroll
            for (int i = 0; i < 4; i++)
                af[i] = *(const v8s*)(&sh[cur * 8192 + (wm * 64 + i * 16 + l16) * 64
                                          + ((ks * 4 + quad) ^ xsw) * 8]);
#pragma unroll
            for (int j = 0; j < 4; j++)
                bfr[j] = *(const v8s*)(&sh[16384 + cur * 8192 + (wn * 64 + j * 16 + l16) * 64
                                           + ((ks * 4 + quad) ^ xsw) * 8]);
#pragma unroll
            for (int i = 0; i < 4; i++)
#pragma unroll
                for (int j = 0; j < 4; j++)
                    acc[i][j] = mfma16(af[i], bfr[j], acc[i][j]);
        }
        __syncthreads();       // all ds_reads drained; buf free for overwrite
        cur ^= 1;
    }
    // loop ended with a barrier: sh is dead -> reuse as epilogue staging.

    if constexpr (EPI == 0) {
        const int h = n0 >> 10;            // block-uniform: 0=Q, 1=K, 2=V
        short* stg = sh;                   // [128][136] bf16 (pitch-padded)
        if (h == 2) {
            // V: col-major staging [lc][row]; v4s = 4 consecutive rows (s)
#pragma unroll
            for (int j = 0; j < 4; j++) {
                const int lc = wn * 64 + j * 16 + l16;
                const float bval = bias3[(n0 + lc) & 1023];
#pragma unroll
                for (int i = 0; i < 4; i++) {
                    const int row0 = wm * 64 + i * 16 + quad * 4;
                    v4s ov = { f2bf(acc[i][j][0] + bval), f2bf(acc[i][j][1] + bval),
                               f2bf(acc[i][j][2] + bval), f2bf(acc[i][j][3] + bval) };
                    *(v4s*)(stg + lc * 136 + row0) = ov;
                }
            }
            __syncthreads();
#pragma unroll
            for (int c8 = 0; c8 < 8; ++c8) {
                const int lin = c8 * 256 + tid;
                const int lc = lin >> 4, ch = lin & 15;
                const int gcol = n0 + lc;
                const int hh = (gcol >> 6) & 15, d = gcol & 63;
                const int grow = m0 + ch * 8;
                const int b_ = grow >> 11, s0 = grow & (SS - 1);
                const v8s v = *(const v8s*)(stg + lc * 136 + ch * 8);
                *(v8s*)((short*)out2 + ((size_t)(b_ * NHH + hh) * DD + d) * SS + s0) = v;
            }
        } else {
            const float* bp = (h == 0) ? bias : bias2;
#pragma unroll
            for (int j = 0; j < 4; j++) {
                const int lc = wn * 64 + j * 16 + l16;
                const int col = n0 + lc;
                const float bval = bp[col & 1023];
                const int d = col & 63;
#pragma unroll
                for (int i = 0; i < 4; i++) {
#pragma unroll
                    for (int r = 0; r < 4; r++) {
                        const int row = wm * 64 + i * 16 + quad * 4 + r;
                        float v = acc[i][j][r] + bval;
                        if (h == 0) v *= oscale;
                        const int s = (m0 + row) & (SS - 1);
                        const float cv = ropeC[s * 32 + (d >> 1)];
                        const float sv = ropeS[s * 32 + (d >> 1)];
                        const float partner = __shfl_xor(v, 1);
                        const float o = (d & 1) ? fmaf(v, cv, partner * sv)
                                                : fmaf(v, cv, -partner * sv);
                        stg[row * 136 + lc] = f2bf(o);
                    }
                }
            }
            __syncthreads();
            const size_t hbase = (size_t)h * (BHN * SS * DD);
#pragma unroll
            for (int c8 = 0; c8 < 8; ++c8) {
                const int lin = c8 * 256 + tid;
                const int row = lin >> 4, ch = lin & 15;
                const int grow = m0 + row;
                const int b_ = grow >> 11, s = grow & (SS - 1);
                const int gcol = n0 + ch * 8;
                const int hh = (gcol >> 6) & 15, d = gcol & 63;
                const v8s v = *(const v8s*)(stg + row * 136 + ch * 8);
                *(v8s*)((short*)out + hbase
                        + (((size_t)(b_ * NHH + hh)) * SS + s) * DD + d) = v;
            }
        }
    } else if constexpr (EPI == 3) {
        short* stg = sh;                   // [128][136] bf16
#pragma unroll
        for (int j = 0; j < 4; j++) {
            const int lc = wn * 64 + j * 16 + l16;
            const float bval = bias[n0 + lc];
#pragma unroll
            for (int i = 0; i < 4; i++) {
#pragma unroll
                for (int r = 0; r < 4; r++) {
                    const int row = wm * 64 + i * 16 + quad * 4 + r;
                    float v = acc[i][j][r] + bval;
                    // gelu(v) = v * sigmoid(2u), u = 0.7978845608*(v + 0.044715 v^3)
                    const float tq = v * v;
                    const float u = v * fmaf(0.035677408136f, tq, 0.7978845608028654f);
                    const float e = __builtin_amdgcn_exp2f(-2.8853900817779268f * u);
                    const float g = v * __builtin_amdgcn_rcpf(1.f + e);
                    stg[row * 136 + lc] = f2bf(g);
                }
            }
        }
        __syncthreads();
#pragma unroll
        for (int c8 = 0; c8 < 8; ++c8) {
            const int lin = c8 * 256 + tid;
            const int row = lin >> 4, ch = lin & 15;
            const v8s v = *(const v8s*)(stg + row * 136 + ch * 8);
            *(v8s*)((short*)out + (size_t)(m0 + row) * N + n0 + ch * 8) = v;
        }
    } else {
        float* stg = (float*)sh;           // [128][128] fp32 = 64 KB exactly
#pragma unroll
        for (int j = 0; j < 4; j++) {
            const int lc = wn * 64 + j * 16 + l16;
            const float bval = bias[n0 + lc];
#pragma unroll
            for (int i = 0; i < 4; i++) {
#pragma unroll
                for (int r = 0; r < 4; r++) {
                    const int row = wm * 64 + i * 16 + quad * 4 + r;
                    stg[row * 128 + lc] = acc[i][j][r] + bval;
                }
            }
        }
        __syncthreads();
        // 128x128 fp32 tile = 4096 float4 chunks = 16 iters x 256 threads
#pragma unroll
        for (int c4 = 0; c4 < 16; ++c4) {
            const int lin = c4 * 256 + tid;
            const int row = lin >> 5, ch = lin & 31;
            float4 v = *(const float4*)(stg + row * 128 + ch * 4);
            const size_t gi = (size_t)(m0 + row) * N + n0 + ch * 4;
            if constexpr (EPI == 2) {
                const float4 rv = *(const float4*)((const float*)resid + gi);
                v.x += rv.x; v.y += rv.y; v.z += rv.z; v.w += rv.w;
            } else {
                const v4s rb = *(const v4s*)((const short*)resid + gi);
                v.x += bf2f(rb[0]); v.y += bf2f(rb[1]);
                v.z += bf2f(rb[2]); v.w += bf2f(rb[3]);
            }
            *(float4*)((float*)out + gi) = v;
        }
    }
}

// ---------------- flash attention (single-buffered) -------------------------
// R10: XCD swizzle (XCD owns 8 bh x all q-tiles -> K/V reused from private L2)
// + setprio(1) around MFMA clusters (T5, +4-7% on independent-block attn).
__global__ __launch_bounds__(256, 4) void attn_kernel(
    const short* __restrict__ Qh, const short* __restrict__ Kh,
    const short* __restrict__ Vt, short* __restrict__ ctx)
{
    __shared__ short Ks[64 * 64];     // [key][d-chunk swizzled]
    __shared__ short Vs[64 * 64];     // [d][key-chunk swizzled]
    __shared__ short Ps[4][16 * 88];  // per-wave P buffer [q][key], pitch 88
    __shared__ float Li[4][32];
    // XCD-aware remap: grid (64 bh, 16 q); p = xcd + 8t -> bh = xcd*8+(t&7)
    const int flat = blockIdx.x + (blockIdx.y << 6);
    const int xcd = flat & 7, tt = flat >> 3;
    const int bh = (xcd << 3) + (tt & 7);
    const int q0 = (tt >> 3) << 7;
    const int t = threadIdx.x, wave = t >> 6, lane = t & 63;
    const int quad = lane >> 4, l16 = lane & 15;

    // Q fragments (B-operand): lane = query q0 + wave*32 + qs*16 + l16
    const short* qp = Qh + ((size_t)bh * SS + q0 + wave * 32 + l16) * DD;
    v8s bq[2][2];
    bq[0][0] = *(const v8s*)(qp + quad * 8);
    bq[0][1] = *(const v8s*)(qp + 32 + quad * 8);
    bq[1][0] = *(const v8s*)(qp + (size_t)16 * DD + quad * 8);
    bq[1][1] = *(const v8s*)(qp + (size_t)16 * DD + 32 + quad * 8);

    v4f o[2][4];
#pragma unroll
    for (int qs = 0; qs < 2; qs++)
#pragma unroll
        for (int c = 0; c < 4; c++) { v4f z = {0.f, 0.f, 0.f, 0.f}; o[qs][c] = z; }
    float li[2] = {0.f, 0.f};

    const short* Kb = Kh + (size_t)bh * SS * DD;
    const short* Vb = Vt + (size_t)bh * DD * SS;
    const int r8 = lane >> 3;                      // row within 8
    const int g8 = (lane & 7) ^ (r8 & 7);          // swizzled source chunk
    short* Psw = (short*)Ps[wave];
    const int xsw = l16 & 7;                       // fragment-read swizzle

    for (int kt = 0; kt < SS; kt += 64) {
        __syncthreads();
        cp16(Ks + wave * 1024,       Kb + (size_t)(kt + wave * 16 + r8) * DD + g8 * 8);
        cp16(Ks + wave * 1024 + 512, Kb + (size_t)(kt + wave * 16 + 8 + r8) * DD + g8 * 8);
        cp16(Vs + wave * 1024,       Vb + (size_t)(wave * 16 + r8) * SS + kt + g8 * 8);
        cp16(Vs + wave * 1024 + 512, Vb + (size_t)(wave * 16 + 8 + r8) * SS + kt + g8 * 8);
        __syncthreads();

        // S^T = K Q^T : D[m=key][n=q]; sc[qs][c][r] = score(key=c*16+quad*4+r, q)
        v4f sc[2][4];
        __builtin_amdgcn_s_setprio(1);
#pragma unroll
        for (int c = 0; c < 4; c++) {
            const v8s k0f = *(const v8s*)(Ks + (c * 16 + l16) * 64 + ((quad    ) ^ xsw) * 8);
            const v8s k1f = *(const v8s*)(Ks + (c * 16 + l16) * 64 + ((quad + 4) ^ xsw) * 8);
#pragma unroll
            for (int qs = 0; qs < 2; qs++) {
                v4f z = {0.f, 0.f, 0.f, 0.f};
                z = mfma16(k0f, bq[qs][0], z);
                z = mfma16(k1f, bq[qs][1], z);
                sc[qs][c] = z;
            }
        }
        __builtin_amdgcn_s_setprio(0);

        // softmax (no max): p = exp2(score); li in fp32; P -> LDS via packed
        // bf16 TRUNCATION (v_perm_b32, 1 op / 2 elems) + ds_write_b64
        v8s pa[2][2];
#pragma unroll
        for (int qs = 0; qs < 2; qs++) {
            float lp = 0.f;
#pragma unroll
            for (int c = 0; c < 4; c++) {
#pragma unroll
                for (int r = 0; r < 4; r++) {
                    const float p = __builtin_amdgcn_exp2f(sc[qs][c][r]);
                    sc[qs][c][r] = p;
                    lp += p;
                }
            }
            li[qs] += lp;
            short* pw = Psw + l16 * 88;
#pragma unroll
            for (int c = 0; c < 4; c++) {
                uint2 w;
                w.x = pktrunc(sc[qs][c][0], sc[qs][c][1]);
                w.y = pktrunc(sc[qs][c][2], sc[qs][c][3]);
                *(uint2*)(pw + c * 16 + quad * 4) = w;
            }
            pa[qs][0] = *(const v8s*)(Psw + l16 * 88 + quad * 8);
            pa[qs][1] = *(const v8s*)(Psw + l16 * 88 + 32 + quad * 8);
        }

        // O += P V : A=P[q][key], B=Vs[d][key]
        __builtin_amdgcn_s_setprio(1);
#pragma unroll
        for (int c = 0; c < 4; c++) {
            const v8s v0f = *(const v8s*)(Vs + (c * 16 + l16) * 64 + ((quad    ) ^ xsw) * 8);
            const v8s v1f = *(const v8s*)(Vs + (c * 16 + l16) * 64 + ((quad + 4) ^ xsw) * 8);
#pragma unroll
            for (int qs = 0; qs < 2; qs++) {
                o[qs][c] = mfma16(pa[qs][0], v0f, o[qs][c]);
                o[qs][c] = mfma16(pa[qs][1], v1f, o[qs][c]);
            }
        }
        __builtin_amdgcn_s_setprio(0);
    }

    // finalize li (cross-quad, once) and divide
    float linv[2][4];
#pragma unroll
    for (int qs = 0; qs < 2; qs++) {
        float lf = li[qs];
        lf += __shfl_xor(lf, 16);
        lf += __shfl_xor(lf, 32);
        if (quad == 0) Li[wave][qs * 16 + l16] = lf;
    }
    __syncthreads();
#pragma unroll
    for (int qs = 0; qs < 2; qs++) {
        const v4f lv = *(const v4f*)(&Li[wave][qs * 16 + quad * 4]);
#pragma unroll
        for (int r = 0; r < 4; r++) linv[qs][r] = __builtin_amdgcn_rcpf(lv[r]);
    }
    const int b_ = bh >> 4, h_ = bh & 15;
#pragma unroll
    for (int qs = 0; qs < 2; qs++)
#pragma unroll
        for (int c = 0; c < 4; c++)
#pragma unroll
            for (int r = 0; r < 4; r++) {
                const int s = q0 + wave * 32 + qs * 16 + quad * 4 + r;
                const int d = c * 16 + l16;
                ctx[((size_t)(b_ * SS + s)) * HD + h_ * DD + d] =
                    f2bf(o[qs][c][r] * linv[qs][r]);
            }
}

// ---------------- LayerNorm (row = 1024) ----------------
__global__ __launch_bounds__(256) void ln_kernel(
    const float* __restrict__ X, const float* __restrict__ g, const float* __restrict__ b,
    float* __restrict__ Y, short* __restrict__ Yb)
{
    const int row = blockIdx.x;
    const int t = threadIdx.x;
    const float4 v = *(const float4*)(X + (size_t)row * HD + t * 4);
    float s = v.x + v.y + v.z + v.w;
    float sq = v.x * v.x + v.y * v.y + v.z * v.z + v.w * v.w;
#pragma unroll
    for (int m = 1; m < 64; m <<= 1) { s += __shfl_xor(s, m); sq += __shfl_xor(sq, m); }
    __shared__ float red[8];
    const int wave = t >> 6, lane = t & 63;
    if (lane == 0) { red[wave] = s; red[4 + wave] = sq; }
    __syncthreads();
    s  = red[0] + red[1] + red[2] + red[3];
    sq = red[4] + red[5] + red[6] + red[7];
    const float mu = s * (1.f / HD);
    const float var = sq * (1.f / HD) - mu * mu;
    const float rs = rsqrtf(var + 1e-12f);
    const float4 gg = *(const float4*)(g + t * 4);
    const float4 bb = *(const float4*)(b + t * 4);
    const float y0 = (v.x - mu) * rs * gg.x + bb.x;
    const float y1 = (v.y - mu) * rs * gg.y + bb.y;
    const float y2 = (v.z - mu) * rs * gg.z + bb.z;
    const float y3 = (v.w - mu) * rs * gg.w + bb.w;
    if (Y)  { float4 o = { y0, y1, y2, y3 }; *(float4*)(Y + (size_t)row * HD + t * 4) = o; }
    if (Yb) { v4s o = { f2bf(y0), f2bf(y1), f2bf(y2), f2bf(y3) };
              *(v4s*)(Yb + (size_t)row * HD + t * 4) = o; }
}

// ---------------- launch ----------------
extern "C" void kernel_launch(void* const* d_in, const int* in_sizes, int n_in,
                              void* d_out, int out_size, void* d_ws, size_t ws_size,
                              hipStream_t stream)
{
    (void)in_sizes; (void)n_in; (void)out_size;
    const float* x   = (const float*)d_in[0];
    const float* Wq  = (const float*)d_in[1];
    const float* bq  = (const float*)d_in[2];
    const float* Wk  = (const float*)d_in[3];
    const float* bk  = (const float*)d_in[4];
    const float* Wv  = (const float*)d_in[5];
    const float* bv  = (const float*)d_in[6];
    const float* Wo  = (const float*)d_in[7];
    const float* bo  = (const float*)d_in[8];
    const float* g1  = (const float*)d_in[9];
    const float* be1 = (const float*)d_in[10];
    const float* W1  = (const float*)d_in[11];
    const float* b1  = (const float*)d_in[12];
    const float* W2  = (const float*)d_in[13];
    const float* b2  = (const float*)d_in[14];
    const float* g2  = (const float*)d_in[15];
    const float* be2 = (const float*)d_in[16];

    char* ws = (char*)d_ws;
    size_t off = 0;
    auto alloc = [&](size_t sz) { char* p = ws + off; off += sz; return p; };
    short* xb    = (short*)alloc((size_t)BS * HD * 2);
    short* WqkvT = (short*)alloc((size_t)3 * HD * HD * 2);  // [3072][1024]
    short* WoT   = (short*)alloc((size_t)HD * HD * 2);
    short* W1T   = (short*)alloc((size_t)FFF * HD * 2);
    short* W2T   = (short*)alloc((size_t)HD * FFF * 2);
    float* ropeC = (float*)alloc((size_t)SS * 32 * 4);
    float* ropeS = (float*)alloc((size_t)SS * 32 * 4);
    short* Qh    = (short*)alloc((size_t)BHN * SS * DD * 2);  // Qh,Kh contiguous
    short* Kh    = (short*)alloc((size_t)BHN * SS * DD * 2);
    short* Vt    = (short*)alloc((size_t)BHN * SS * DD * 2);  // [bh][d][s]
    short* ctx   = (short*)alloc((size_t)BS * HD * 2);
    float* ao    = (float*)alloc((size_t)BS * HD * 4);
    if (off > ws_size) return;
    short* f1 = Qh;              // alias: Qh..ctx span (64MB) dead before FFN1
    short* hb = xb;              // alias: xb dead after QKV projections
    float* f2 = (float*)d_out;   // FFN2 output staged in d_out, LN2 in-place

    // Q pre-scale: 1/sqrt(D) * log2(e) so attention uses exp2 directly
    const float qsc = 0.125f * 1.4426950408889634f;

    prep_all<<<11520, 256, 0, stream>>>(x, xb, ropeC, ropeS,
                                        Wq, Wk, Wv, Wo, W1, W2,
                                        WqkvT, WoT, W1T, W2T);

    // fused QKV: N = 3072 -> Qh/Kh (head layout) + Vt (transposed) directly
    gemm128<0><<<dim3(64, 24), 256, 0, stream>>>(xb, WqkvT, bq, bk, bv, Qh, Vt,
                                                 nullptr, ropeC, ropeS, BS, 3 * HD, HD, qsc);
    attn_kernel<<<dim3(64, SS / 128), 256, 0, stream>>>(Qh, Kh, Vt, ctx);
    gemm128<2><<<dim3(64, 8), 256, 0, stream>>>(ctx, WoT, bo, nullptr, nullptr, ao,
                                                nullptr, x, nullptr, nullptr, BS, HD, HD, 1.0f);
    ln_kernel<<<BS, 256, 0, stream>>>(ao, g1, be1, nullptr, hb);
    gemm128<3><<<dim3(64, 32), 256, 0, stream>>>(hb, W1T, b1, nullptr, nullptr, f1,
                                                 nullptr, nullptr, nullptr, nullptr, BS, FFF, HD, 1.0f);
    gemm128<4><<<dim3(64, 8), 256, 0, stream>>>(f1, W2T, b2, nullptr, nullptr, f2,
                                                nullptr, hb, nullptr, nullptr, BS, HD, FFF, 1.0f);
    ln_kernel<<<BS, 256, 0, stream>>>(f2, g2, be2, (float*)d_out, nullptr);
}